// Round 5
// baseline (1026.038 us; speedup 1.0000x reference)
//
#include <hip/hip_runtime.h>
#include <cstdint>

namespace {
constexpr int B = 16, C = 256, N = 16384, K = 64;
constexpr float TEMP = 20.0f, EPS = 1e-6f;
// zT row stride in halfwords: 528 B/row, 16B-aligned, spreads b128 reads.
constexpr int ZRS = 264;
}

typedef _Float16 f16x8 __attribute__((ext_vector_type(8)));
typedef float f32x4 __attribute__((ext_vector_type(4)));

__device__ __forceinline__ uint32_t pack2(_Float16 a, _Float16 b) {
  union { _Float16 h[2]; uint32_t u; } t;
  t.h[0] = a; t.h[1] = b;
  return t.u;
}

// ---------------------------------------------------------------------------
// kprep: one-shot layout transform.
//   xT16 hi/lo [b][n][C] fp16  (phase-1 A-operand: 8 consecutive c per lane)
//   xc16       [b][c][N] fp16  (phase-2 A-operand: 8 consecutive n per lane)
// Block = [64 c][256 n] tile. Stage A: coalesced float2 loads, cvt hi/lo,
// write xc16 (hi) + LDS tiles. Stage B: transpose-read LDS (conflict-free:
// lane-pairs broadcast one word, 32 words -> 32 banks), repack halves,
// b128 row-stores (row n segment = full/half cache lines via L2).
// ---------------------------------------------------------------------------
__global__ __launch_bounds__(256, 2) void kprep_kernel(
    const float* __restrict__ x, _Float16* __restrict__ xTh,
    _Float16* __restrict__ xTl, _Float16* __restrict__ xc) {
  __shared__ uint32_t LH[64 * 128], LL[64 * 128];  // 64 KB
  const int tid = threadIdx.x;
  const int n0 = blockIdx.x * 256;   // n tile
  const int cb = blockIdx.y * 64;    // c tile
  const int b = blockIdx.z;
  const int tt = tid & 127, chh = tid >> 7;

  const float2* xs =
      (const float2*)(x + ((size_t)b * C + cb) * N + n0);  // row stride N/2
  uint32_t* xcw = (uint32_t*)xc;

#pragma unroll
  for (int r = 0; r < 32; ++r) {
    const int cl = chh * 32 + r;
    const float2 v = xs[(size_t)cl * (N / 2) + tt];
    const _Float16 h0 = (_Float16)v.x, h1 = (_Float16)v.y;
    const _Float16 l0 = (_Float16)(v.x - (float)h0);
    const _Float16 l1 = (_Float16)(v.y - (float)h1);
    const uint32_t hw = pack2(h0, h1), lw = pack2(l0, l1);
    LH[cl * 128 + tt] = hw;
    LL[cl * 128 + tt] = lw;
    xcw[((size_t)b * C + cb + cl) * (N / 2) + (n0 / 2) + tt] = hw;
  }
  __syncthreads();

  // stage B: thread owns xT row n = n0 + tid, c-segment [cb, cb+64)
  const int p = tid & 1, t2 = tid >> 1;
  uint32_t oh[32], ol[32];
#pragma unroll
  for (int j = 0; j < 32; ++j) {
    const uint32_t a0 = LH[(2 * j) * 128 + t2];
    const uint32_t a1 = LH[(2 * j + 1) * 128 + t2];
    oh[j] = p ? ((a0 >> 16) | (a1 & 0xffff0000u))
              : ((a0 & 0xffffu) | (a1 << 16));
    const uint32_t b0 = LL[(2 * j) * 128 + t2];
    const uint32_t b1 = LL[(2 * j + 1) * 128 + t2];
    ol[j] = p ? ((b0 >> 16) | (b1 & 0xffff0000u))
              : ((b0 & 0xffffu) | (b1 << 16));
  }
  uint32_t* dh = (uint32_t*)xTh + ((size_t)b * N + n0 + tid) * 128 + (cb / 2);
  uint32_t* dl = (uint32_t*)xTl + ((size_t)b * N + n0 + tid) * 128 + (cb / 2);
#pragma unroll
  for (int j = 0; j < 8; ++j) {
    *(uint4*)(dh + 4 * j) =
        make_uint4(oh[4 * j], oh[4 * j + 1], oh[4 * j + 2], oh[4 * j + 3]);
    *(uint4*)(dl + 4 * j) =
        make_uint4(ol[4 * j], ol[4 * j + 1], ol[4 * j + 2], ol[4 * j + 3]);
  }
}

// muT16 hi/lo [64 k][256 c] from mu[256 c][64 k] (b-shared, step 0)
__global__ __launch_bounds__(256) void kmuT_kernel(const float* __restrict__ mu,
                                                   _Float16* __restrict__ muTh,
                                                   _Float16* __restrict__ muTl) {
  const int k = blockIdx.x, c = threadIdx.x;
  const float v = mu[c * K + k];
  const _Float16 h = (_Float16)v;
  muTh[k * 256 + c] = h;
  muTl[k * 256 + c] = (_Float16)(v - (float)h);
}

// ---------------------------------------------------------------------------
// Fused EM step. Block = 256 n's of one batch, 4 waves. NO LDS / NO barriers
// in phase 1: A-frags stream directly from xT16 hi/lo; B-frags from mT16
// (64 KB per b, L2-resident). 48 MFMA per 32-c chunk (hh+hl+lh).
// Softmax in MFMA D-layout. FINAL: fp32 out, done.
// Phase 2: zT fp16 in LDS (the only LDS use, 33 KB), S col-sums,
// m'[c][k] += x.z with A-frags as direct b128 loads from xc16, atomics to mt.
// ---------------------------------------------------------------------------
template <bool FINAL>
__global__ __launch_bounds__(256, 2) void kstep_kernel(
    const _Float16* __restrict__ xTh, const _Float16* __restrict__ xTl,
    const _Float16* __restrict__ xc, const _Float16* __restrict__ mTh,
    const _Float16* __restrict__ mTl,
    const long mTbs,               // 0 (step 0: muT broadcast) or 64*256
    float* __restrict__ mt,        // [B][C][K] accum (pre-zeroed)
    float* __restrict__ S,         // [B][K] accum (pre-zeroed)
    float* __restrict__ out) {     // [B][N][K] fp32
  __shared__ __attribute__((aligned(16))) _Float16 zt[64 * ZRS];  // 33 KB
  const int tid = threadIdx.x;
  const int b = blockIdx.y;
  const int n0 = blockIdx.x * 256;
  const int w = tid >> 6;
  const int lane = tid & 63;
  const int lr = lane & 15, lh = lane >> 4;

  // ---- phase 1: scores via MFMA, barrier-free stream ----
  f32x4 acc[4][4];
#pragma unroll
  for (int mi = 0; mi < 4; ++mi)
#pragma unroll
    for (int ni = 0; ni < 4; ++ni) acc[mi][ni] = (f32x4){0.f, 0.f, 0.f, 0.f};

  const _Float16* Ah =
      xTh + ((size_t)b * N + n0 + w * 64 + lr) * 256 + lh * 8;  // +mi*4096+ci*32
  const _Float16* Al = xTl + ((size_t)b * N + n0 + w * 64 + lr) * 256 + lh * 8;
  const _Float16* Bh = mTh + (size_t)b * mTbs + (size_t)lr * 256 + lh * 8;
  const _Float16* Bl = mTl + (size_t)b * mTbs + (size_t)lr * 256 + lh * 8;

#pragma unroll 2
  for (int ci = 0; ci < 8; ++ci) {
    const int co = ci * 32;
    f16x8 ah[4], al[4], bh[4], bl[4];
#pragma unroll
    for (int t = 0; t < 4; ++t) {
      ah[t] = *(const f16x8*)(Ah + t * 4096 + co);
      al[t] = *(const f16x8*)(Al + t * 4096 + co);
      bh[t] = *(const f16x8*)(Bh + t * 4096 + co);
      bl[t] = *(const f16x8*)(Bl + t * 4096 + co);
    }
#pragma unroll
    for (int ni = 0; ni < 4; ++ni)
#pragma unroll
      for (int mi = 0; mi < 4; ++mi) {
        acc[mi][ni] = __builtin_amdgcn_mfma_f32_16x16x32_f16(ah[mi], bh[ni],
                                                             acc[mi][ni], 0, 0, 0);
        acc[mi][ni] = __builtin_amdgcn_mfma_f32_16x16x32_f16(ah[mi], bl[ni],
                                                             acc[mi][ni], 0, 0, 0);
        acc[mi][ni] = __builtin_amdgcn_mfma_f32_16x16x32_f16(al[mi], bh[ni],
                                                             acc[mi][ni], 0, 0, 0);
      }
  }

  // ---- softmax over k, in D-layout ----
  // Row n = w*64 + mi*16 + lh*4 + r; its 64 k's = {ni*16+lr} over 16 lr-lanes.
  const float sc = FINAL ? 1.0f : TEMP;  // final einsum has NO temperature
#pragma unroll
  for (int mi = 0; mi < 4; ++mi)
#pragma unroll
    for (int r = 0; r < 4; ++r) {
      float v0 = acc[mi][0][r] * sc, v1 = acc[mi][1][r] * sc;
      float v2 = acc[mi][2][r] * sc, v3 = acc[mi][3][r] * sc;
      float mx = fmaxf(fmaxf(v0, v1), fmaxf(v2, v3));
      mx = fmaxf(mx, __shfl_xor(mx, 1));
      mx = fmaxf(mx, __shfl_xor(mx, 2));
      mx = fmaxf(mx, __shfl_xor(mx, 4));
      mx = fmaxf(mx, __shfl_xor(mx, 8));
      v0 = __expf(v0 - mx); v1 = __expf(v1 - mx);
      v2 = __expf(v2 - mx); v3 = __expf(v3 - mx);
      float s = v0 + v1 + v2 + v3;
      s += __shfl_xor(s, 1);
      s += __shfl_xor(s, 2);
      s += __shfl_xor(s, 4);
      s += __shfl_xor(s, 8);
      const float inv = 1.0f / s;
      acc[mi][0][r] = v0 * inv; acc[mi][1][r] = v1 * inv;
      acc[mi][2][r] = v2 * inv; acc[mi][3][r] = v3 * inv;
    }

  if (FINAL) {
    float* ob = out + ((size_t)b * N + n0 + w * 64) * K;
#pragma unroll
    for (int mi = 0; mi < 4; ++mi)
#pragma unroll
      for (int r = 0; r < 4; ++r) {
        const int row = mi * 16 + lh * 4 + r;
#pragma unroll
        for (int ni = 0; ni < 4; ++ni)
          ob[(size_t)row * K + ni * 16 + lr] = acc[mi][ni][r];
      }
    return;
  }

  // ---- phase 2 ----
  // zT write: 4 contiguous n (r=0..3) at row k -> one b64 write.
#pragma unroll
  for (int mi = 0; mi < 4; ++mi)
#pragma unroll
    for (int ni = 0; ni < 4; ++ni) {
      const uint32_t w0 = pack2((_Float16)acc[mi][ni][0], (_Float16)acc[mi][ni][1]);
      const uint32_t w1 = pack2((_Float16)acc[mi][ni][2], (_Float16)acc[mi][ni][3]);
      *(uint2*)&zt[(ni * 16 + lr) * ZRS + w * 64 + mi * 16 + lh * 4] =
          make_uint2(w0, w1);
    }
  __syncthreads();

  // A-frags (xc16, fp16, direct b128 loads) with 1-deep prefetch
  const int cbase = w * 64;
  const _Float16* Ac =
      xc + ((size_t)b * C + cbase + lr) * N + n0 + lh * 8;  // +mi*16*N + ks*32
  f16x8 acur[4], anxt[4];
#define LOAD_KS(DST, ks)                                             \
  {                                                                  \
    _Pragma("unroll") for (int mi = 0; mi < 4; ++mi)                 \
        DST[mi] = *(const f16x8*)(Ac + (size_t)mi * 16 * N + (ks) * 32); \
  }
  LOAD_KS(acur, 0);

  {  // S[b,k] += sum over this block's n of z; thread = (k, n-quarter)
    const int k = tid & 63, qt = tid >> 6;
    float s = 0.f;
#pragma unroll
    for (int j = 0; j < 8; ++j) {
      f16x8 v = *(const f16x8*)(zt + k * ZRS + qt * 64 + j * 8);
#pragma unroll
      for (int e = 0; e < 8; ++e) s += (float)v[e];
    }
    atomicAdd(&S[b * K + k], s);
  }

  f32x4 acc2[4][4];
#pragma unroll
  for (int mi = 0; mi < 4; ++mi)
#pragma unroll
    for (int ni = 0; ni < 4; ++ni) acc2[mi][ni] = (f32x4){0.f, 0.f, 0.f, 0.f};

#pragma unroll
  for (int ks = 0; ks < 8; ++ks) {
    const int np = ks * 32 + lh * 8;
    if (ks + 1 < 8) LOAD_KS(anxt, ks + 1);  // in flight under the 16 MFMAs
#pragma unroll
    for (int ni = 0; ni < 4; ++ni) {
      const f16x8 bf = *(const f16x8*)(zt + (ni * 16 + lr) * ZRS + np);
#pragma unroll
      for (int mi = 0; mi < 4; ++mi)
        acc2[mi][ni] = __builtin_amdgcn_mfma_f32_16x16x32_f16(acur[mi], bf,
                                                              acc2[mi][ni], 0, 0, 0);
    }
#pragma unroll
    for (int mi = 0; mi < 4; ++mi) acur[mi] = anxt[mi];
  }
#undef LOAD_KS

  // D layout (16x16): col = lane&15 (k), row = (lane>>4)*4 + reg (c).
#pragma unroll
  for (int mi = 0; mi < 4; ++mi)
#pragma unroll
    for (int ni = 0; ni < 4; ++ni) {
      const int k = ni * 16 + lr;
#pragma unroll
      for (int r = 0; r < 4; ++r) {
        const int c = cbase + mi * 16 + lh * 4 + r;
        atomicAdd(&mt[((size_t)b * C + c) * K + k], acc2[mi][ni][r]);
      }
    }
}

// mT16[b,k,c] = l2norm_c( mt[b,:,k] * 1/(EPS+S[b,k]) ), written as fp16 hi/lo.
// Also re-zeroes mt and S for the next EM step.
__global__ __launch_bounds__(64) void kl2_kernel(float* __restrict__ mt,
                                                 float* __restrict__ S,
                                                 _Float16* __restrict__ mTh,
                                                 _Float16* __restrict__ mTl) {
  const int k = blockIdx.x, b = blockIdx.y, lane = threadIdx.x;
  const float s = 1.0f / (EPS + S[b * K + k]);
  float v[4];
  float ss = 0.f;
#pragma unroll
  for (int i = 0; i < 4; ++i) {
    const size_t idx = ((size_t)b * C + lane + 64 * i) * K + k;
    v[i] = mt[idx] * s;
    mt[idx] = 0.f;  // re-zero for next step's atomics
    ss += v[i] * v[i];
  }
  if (lane == 0) S[b * K + k] = 0.f;
#pragma unroll
  for (int off = 32; off >= 1; off >>= 1) ss += __shfl_xor(ss, off);
  const float inv = 1.0f / (EPS + sqrtf(ss));
#pragma unroll
  for (int i = 0; i < 4; ++i) {
    const float val = v[i] * inv;
    const _Float16 h = (_Float16)val;
    const size_t o = ((size_t)b * K + k) * 256 + lane + 64 * i;
    mTh[o] = h;
    mTl[o] = (_Float16)(val - (float)h);
  }
}

__global__ __launch_bounds__(256) void kzero_kernel(float* __restrict__ p, int ntot) {
  const int i = blockIdx.x * 256 + threadIdx.x;
  if (i < ntot) p[i] = 0.f;
}

extern "C" void kernel_launch(void* const* d_in, const int* in_sizes, int n_in,
                              void* d_out, int out_size, void* d_ws,
                              size_t ws_size, hipStream_t stream) {
  const float* x = (const float*)d_in[0];   // fp32 [B][C][N]
  const float* mu = (const float*)d_in[1];  // fp32 [1][C][K]
  float* out = (float*)d_out;               // fp32 [B][N][K]

  // ws layout: xT16 hi | xT16 lo | xc16 | mT16 hi | mT16 lo | muT hi | muT lo
  //            | mt (fp32) | S (fp32)   -- ~405 MB total
  const size_t SZ_XT = (size_t)B * N * C * 2;      // 134 MB
  const size_t SZ_MT = (size_t)B * K * 256 * 2;    // 512 KB
  const size_t SZ_MU = (size_t)K * 256 * 2;        // 32 KB
  char* p = (char*)d_ws;
  _Float16* xTh = (_Float16*)p; p += SZ_XT;
  _Float16* xTl = (_Float16*)p; p += SZ_XT;
  _Float16* xc  = (_Float16*)p; p += SZ_XT;
  _Float16* mTh = (_Float16*)p; p += SZ_MT;
  _Float16* mTl = (_Float16*)p; p += SZ_MT;
  _Float16* muTh = (_Float16*)p; p += SZ_MU;
  _Float16* muTl = (_Float16*)p; p += SZ_MU;
  float* mt = (float*)p; p += (size_t)B * C * K * 4;
  float* S = (float*)p;
  const int nz = B * C * K + B * K;  // mt + S contiguous

  kprep_kernel<<<dim3(N / 256, C / 64, B), 256, 0, stream>>>(x, xTh, xTl, xc);
  kmuT_kernel<<<K, 256, 0, stream>>>(mu, muTh, muTl);
  kzero_kernel<<<(nz + 255) / 256, 256, 0, stream>>>(mt, nz);
  for (int step = 0; step < 3; ++step) {
    const _Float16* mh = step == 0 ? muTh : mTh;
    const _Float16* ml = step == 0 ? muTl : mTl;
    const long mbs = step == 0 ? 0 : (long)K * 256;
    kstep_kernel<false><<<dim3(N / 256, B), 256, 0, stream>>>(
        xTh, xTl, xc, mh, ml, mbs, mt, S, nullptr);
    kl2_kernel<<<dim3(K, B), 64, 0, stream>>>(mt, S, mTh, mTl);
  }
  kstep_kernel<true><<<dim3(N / 256, B), 256, 0, stream>>>(
      xTh, xTl, xc, mTh, mTl, (long)K * 256, nullptr, nullptr, out);
}

// Round 6
// 914.140 us; speedup vs baseline: 1.1224x; 1.1224x over previous
//
#include <hip/hip_runtime.h>
#include <cstdint>

namespace {
constexpr int B = 16, C = 256, N = 16384, K = 64;
constexpr float TEMP = 20.0f, EPS = 1e-6f;
constexpr int NB = 128;          // n per block (halved: occupancy over tile size)
constexpr int ZRS = 136;         // zt row stride (hw): 272 B, odd 16B-slot count
// phase-1 LDS (u32 units): xT hi/lo [128 n][16 u32], mT hi/lo [64 k][16 u32]
constexpr int XTH = 0, XTL = 2048, MTH = 4096, MTL = 5120;
constexpr int SMU_SIZE = 6144;   // 24 KB; phase-2 zt (64*136*2 = 17 KB) reuses it
}

typedef _Float16 f16x8 __attribute__((ext_vector_type(8)));
typedef float f32x4 __attribute__((ext_vector_type(4)));

__device__ __forceinline__ uint32_t pack2(_Float16 a, _Float16 b) {
  union { _Float16 h[2]; uint32_t u; } t;
  t.h[0] = a; t.h[1] = b;
  return t.u;
}

__device__ __forceinline__ void hilo(float v0, float v1, uint32_t& hp, uint32_t& lp) {
  const _Float16 h0 = (_Float16)v0, h1 = (_Float16)v1;
  const _Float16 l0 = (_Float16)(v0 - (float)h0);
  const _Float16 l1 = (_Float16)(v1 - (float)h1);
  hp = pack2(h0, h1);
  lp = pack2(l0, l1);
}

// Slot-swizzled u32 index into a row-major [rows][16 u32] LDS tile.
// Per 16-lane LDS phase both the b128 writes and fragment reads land 2
// lanes/bank (free per m136).
__device__ __forceinline__ int swz(int row, int slot) {
  return row * 16 + 4 * (slot ^ ((row >> 1) & 3));
}

// Raw barrier: drains LDS (lgkmcnt) only; global loads stay in flight.
#define BAR()                                              \
  do {                                                     \
    asm volatile("s_waitcnt lgkmcnt(0)" ::: "memory");     \
    __builtin_amdgcn_s_barrier();                          \
  } while (0)

// Fused EM step. Block = 128 n of one batch, 4 waves; wave tile 32n x 64k.
// acc[2][4] = 32 accum regs -> total reg budget <=128 -> 4 waves/SIMD
// (the round-5 postmortem lever: occupancy 20% -> ~45%).
// Phase 1 (MFMA): Z = xT . m, c chunked by 32, x/m fp16 hi+lo (hh+hl+lh).
// Softmax in MFMA D-layout. FINAL: fp32 out, done.
// Phase 2 (MFMA): zT fp16 in LDS, S col-sums, m' += x.z in two 32-c passes
// per wave (reusing the same 32 accum regs), atomics into mt.
template <bool FINAL>
__global__ __launch_bounds__(256, 4) void kstep_kernel(
    const float* __restrict__ x,   // [B][C][N] fp32
    const float* __restrict__ m,   // [B][C][K] fp32 (or mu with mstride=0)
    const int mstride,             // 0 (step 0: mu broadcast) or C*K
    float* __restrict__ mt,        // [B][C][K] accum (pre-zeroed)
    float* __restrict__ S,         // [B][K] accum (pre-zeroed)
    float* __restrict__ out) {     // [B][N][K] fp32
  __shared__ __attribute__((aligned(16))) uint32_t smu[SMU_SIZE];
  const int tid = threadIdx.x;
  const int b = blockIdx.y;
  const int n0 = blockIdx.x * NB;
  const int w = tid >> 6;
  const int lane = tid & 63;
  const int lr = lane & 15, lh = lane >> 4;
  const int nr = tid & 127, ch = tid >> 7;  // x-stage: row n, c-half

  // ---- phase 1 ----
  f32x4 acc[2][4];
#pragma unroll
  for (int mi = 0; mi < 2; ++mi)
#pragma unroll
    for (int ni = 0; ni < 4; ++ni) acc[mi][ni] = (f32x4){0.f, 0.f, 0.f, 0.f};

  const float* xcol = x + (size_t)b * C * N + n0 + nr;  // + c*N
  const float* mrow = m + (size_t)b * mstride + lane;   // + c*K

  float xv[16], mv[8];
#define LOADX(CI)                                                    \
  {                                                                  \
    const int cc = (CI) * 32 + 16 * ch;                              \
    _Pragma("unroll") for (int j = 0; j < 16; ++j)                   \
        xv[j] = xcol[(size_t)(cc + j) * N];                          \
  }
#define LOADM(CI)                                                    \
  {                                                                  \
    const int cc = (CI) * 32 + 8 * w;                                \
    _Pragma("unroll") for (int j = 0; j < 8; ++j)                    \
        mv[j] = mrow[(size_t)(cc + j) * K];                          \
  }

  LOADX(0); LOADM(0);

  for (int ci = 0; ci < 8; ++ci) {
    BAR();  // previous chunk's fragment reads done (lgkm only)
    // pack xv -> xT hi/lo: row nr, slots {2ch, 2ch+1}
#pragma unroll
    for (int s2 = 0; s2 < 2; ++s2) {
      uint32_t hp[4], lp[4];
#pragma unroll
      for (int jj = 0; jj < 4; ++jj)
        hilo(xv[8 * s2 + 2 * jj], xv[8 * s2 + 2 * jj + 1], hp[jj], lp[jj]);
      const int e = swz(nr, 2 * ch + s2);
      *(uint4*)&smu[XTH + e] = make_uint4(hp[0], hp[1], hp[2], hp[3]);
      *(uint4*)&smu[XTL + e] = make_uint4(lp[0], lp[1], lp[2], lp[3]);
    }
    {  // pack mv -> mT hi/lo: row k=lane, slot w
      uint32_t hp[4], lp[4];
#pragma unroll
      for (int jj = 0; jj < 4; ++jj)
        hilo(mv[2 * jj], mv[2 * jj + 1], hp[jj], lp[jj]);
      const int e = swz(lane, w);
      *(uint4*)&smu[MTH + e] = make_uint4(hp[0], hp[1], hp[2], hp[3]);
      *(uint4*)&smu[MTL + e] = make_uint4(lp[0], lp[1], lp[2], lp[3]);
    }
    BAR();  // writes visible
    if (ci + 1 < 8) { LOADX(ci + 1); LOADM(ci + 1); }  // in flight across MFMAs
    __builtin_amdgcn_sched_barrier(0);

    f16x8 ah[2], al[2];
#pragma unroll
    for (int mi = 0; mi < 2; ++mi) {
      const int ea = swz(w * 32 + mi * 16 + lr, lh);
      ah[mi] = *(const f16x8*)&smu[XTH + ea];
      al[mi] = *(const f16x8*)&smu[XTL + ea];
    }
#pragma unroll
    for (int ni = 0; ni < 4; ++ni) {
      const int eb = swz(ni * 16 + lr, lh);
      const f16x8 bh = *(const f16x8*)&smu[MTH + eb];
      const f16x8 bl = *(const f16x8*)&smu[MTL + eb];
#pragma unroll
      for (int mi = 0; mi < 2; ++mi) {
        acc[mi][ni] =
            __builtin_amdgcn_mfma_f32_16x16x32_f16(ah[mi], bh, acc[mi][ni], 0, 0, 0);
        acc[mi][ni] =
            __builtin_amdgcn_mfma_f32_16x16x32_f16(ah[mi], bl, acc[mi][ni], 0, 0, 0);
        acc[mi][ni] =
            __builtin_amdgcn_mfma_f32_16x16x32_f16(al[mi], bh, acc[mi][ni], 0, 0, 0);
      }
    }
  }
#undef LOADM
#undef LOADX

  // ---- softmax over k, in D-layout ----
  // Row n = w*32 + mi*16 + lh*4 + r; 64 k's = {ni*16+lr} across 16 lr-lanes.
  const float sc = FINAL ? 1.0f : TEMP;  // final einsum has NO temperature
#pragma unroll
  for (int mi = 0; mi < 2; ++mi)
#pragma unroll
    for (int r = 0; r < 4; ++r) {
      float v0 = acc[mi][0][r] * sc, v1 = acc[mi][1][r] * sc;
      float v2 = acc[mi][2][r] * sc, v3 = acc[mi][3][r] * sc;
      float mx = fmaxf(fmaxf(v0, v1), fmaxf(v2, v3));
      mx = fmaxf(mx, __shfl_xor(mx, 1));
      mx = fmaxf(mx, __shfl_xor(mx, 2));
      mx = fmaxf(mx, __shfl_xor(mx, 4));
      mx = fmaxf(mx, __shfl_xor(mx, 8));
      v0 = __expf(v0 - mx); v1 = __expf(v1 - mx);
      v2 = __expf(v2 - mx); v3 = __expf(v3 - mx);
      float s = v0 + v1 + v2 + v3;
      s += __shfl_xor(s, 1);
      s += __shfl_xor(s, 2);
      s += __shfl_xor(s, 4);
      s += __shfl_xor(s, 8);
      const float inv = 1.0f / s;
      acc[mi][0][r] = v0 * inv; acc[mi][1][r] = v1 * inv;
      acc[mi][2][r] = v2 * inv; acc[mi][3][r] = v3 * inv;
    }

  if (FINAL) {
    float* ob = out + ((size_t)b * N + n0 + w * 32) * K;
#pragma unroll
    for (int mi = 0; mi < 2; ++mi)
#pragma unroll
      for (int r = 0; r < 4; ++r) {
        const int row = mi * 16 + lh * 4 + r;
#pragma unroll
        for (int ni = 0; ni < 4; ++ni)
          ob[(size_t)row * K + ni * 16 + lr] = acc[mi][ni][r];
      }
    return;
  }

  // ---- phase 2 ----
  BAR();  // all fragment reads done before zt overwrites the tile
  _Float16* zt = (_Float16*)smu;  // zT fp16 [64 k][128 n], row stride ZRS
#pragma unroll
  for (int mi = 0; mi < 2; ++mi)
#pragma unroll
    for (int ni = 0; ni < 4; ++ni) {
      const uint32_t w0 = pack2((_Float16)acc[mi][ni][0], (_Float16)acc[mi][ni][1]);
      const uint32_t w1 = pack2((_Float16)acc[mi][ni][2], (_Float16)acc[mi][ni][3]);
      *(uint2*)&zt[(ni * 16 + lr) * ZRS + w * 32 + mi * 16 + lh * 4] =
          make_uint2(w0, w1);
    }
  BAR();

  // prefetch pass 0 / ks 0 (overlaps the S-sum)
  const float* xw = x + (size_t)b * C * N + n0;
  float4 cu[2], cv[2];
#define LOAD_P2(CH2, KS)                                                      \
  {                                                                           \
    const int np = (KS) * 32 + lh * 8;                                        \
    _Pragma("unroll") for (int mi = 0; mi < 2; ++mi) {                        \
      const float* p =                                                        \
          xw + (size_t)(w * 64 + (CH2) * 32 + mi * 16 + lr) * N + np;         \
      cu[mi] = *(const float4*)p;                                             \
      cv[mi] = *(const float4*)(p + 4);                                       \
    }                                                                         \
  }
  LOAD_P2(0, 0);

  {  // S[b,k] += sum over this block's n of z; thread = (k, n-quarter)
    const int k = tid & 63, qt = tid >> 6;
    float s = 0.f;
#pragma unroll
    for (int j = 0; j < 4; ++j) {
      f16x8 v = *(const f16x8*)(zt + k * ZRS + qt * 32 + j * 8);
#pragma unroll
      for (int e = 0; e < 8; ++e) s += (float)v[e];
    }
    atomicAdd(&S[b * K + k], s);
  }

  // m'[c][k] += sum_n x[c][n]*z[n][k]; wave w: c in [w*64, w*64+64), two
  // 32-c passes reusing the same accum registers.
#pragma unroll
  for (int ch2 = 0; ch2 < 2; ++ch2) {
    f32x4 acc2[2][4];
#pragma unroll
    for (int mi = 0; mi < 2; ++mi)
#pragma unroll
      for (int ni = 0; ni < 4; ++ni) acc2[mi][ni] = (f32x4){0.f, 0.f, 0.f, 0.f};

#pragma unroll
    for (int ks = 0; ks < 4; ++ks) {
      const int np = ks * 32 + lh * 8;
      f16x8 af[2];
#pragma unroll
      for (int mi = 0; mi < 2; ++mi) {
        f16x8 t;
        t[0] = (_Float16)cu[mi].x; t[1] = (_Float16)cu[mi].y;
        t[2] = (_Float16)cu[mi].z; t[3] = (_Float16)cu[mi].w;
        t[4] = (_Float16)cv[mi].x; t[5] = (_Float16)cv[mi].y;
        t[6] = (_Float16)cv[mi].z; t[7] = (_Float16)cv[mi].w;
        af[mi] = t;
      }
      if (ks + 1 < 4) {
        LOAD_P2(ch2, ks + 1);
      } else if (ch2 == 0) {
        LOAD_P2(1, 0);
      }
#pragma unroll
      for (int ni = 0; ni < 4; ++ni) {
        const f16x8 bf = *(const f16x8*)(zt + (ni * 16 + lr) * ZRS + np);
#pragma unroll
        for (int mi = 0; mi < 2; ++mi)
          acc2[mi][ni] = __builtin_amdgcn_mfma_f32_16x16x32_f16(
              af[mi], bf, acc2[mi][ni], 0, 0, 0);
      }
    }
    // D layout: col k = ni*16+lr, row c = base + lh*4 + reg
#pragma unroll
    for (int mi = 0; mi < 2; ++mi)
#pragma unroll
      for (int ni = 0; ni < 4; ++ni) {
        const int k = ni * 16 + lr;
#pragma unroll
        for (int r = 0; r < 4; ++r) {
          const int c = w * 64 + ch2 * 32 + mi * 16 + lh * 4 + r;
          atomicAdd(&mt[((size_t)b * C + c) * K + k], acc2[mi][ni][r]);
        }
      }
  }
#undef LOAD_P2
}

// m[b,c,k] = l2norm_c( mt[b,:,k] * 1/(EPS + S[b,k]) ); re-zeroes mt and S.
__global__ __launch_bounds__(64) void kl2_kernel(float* __restrict__ mt,
                                                 float* __restrict__ S,
                                                 float* __restrict__ m) {
  const int k = blockIdx.x, b = blockIdx.y, lane = threadIdx.x;
  const float s = 1.0f / (EPS + S[b * K + k]);
  float v[4];
  float ss = 0.f;
#pragma unroll
  for (int i = 0; i < 4; ++i) {
    const size_t idx = ((size_t)b * C + lane + 64 * i) * K + k;
    v[i] = mt[idx] * s;
    mt[idx] = 0.f;  // re-zero for next step's atomics
    ss += v[i] * v[i];
  }
  if (lane == 0) S[b * K + k] = 0.f;
#pragma unroll
  for (int off = 32; off >= 1; off >>= 1) ss += __shfl_xor(ss, off);
  const float inv = 1.0f / (EPS + sqrtf(ss));
#pragma unroll
  for (int i = 0; i < 4; ++i)
    m[((size_t)b * C + lane + 64 * i) * K + k] = v[i] * inv;
}

__global__ __launch_bounds__(256) void kzero_kernel(float* __restrict__ p, int ntot) {
  const int i = blockIdx.x * 256 + threadIdx.x;
  if (i < ntot) p[i] = 0.f;
}

extern "C" void kernel_launch(void* const* d_in, const int* in_sizes, int n_in,
                              void* d_out, int out_size, void* d_ws,
                              size_t ws_size, hipStream_t stream) {
  const float* x = (const float*)d_in[0];   // fp32 [B][C][N]
  const float* mu = (const float*)d_in[1];  // fp32 [1][C][K]
  float* out = (float*)d_out;               // fp32 [B][N][K]

  // ws layout (fp32): m[B*C*K] | mt[B*C*K] | S[B*K]  (~2.01 MB total)
  float* m = (float*)d_ws;
  float* mt = m + (size_t)B * C * K;
  float* S = mt + (size_t)B * C * K;
  const int nz = B * C * K + B * K;  // mt + S contiguous

  kzero_kernel<<<(nz + 255) / 256, 256, 0, stream>>>(mt, nz);
  for (int step = 0; step < 3; ++step) {
    // step 0 reads mu directly (broadcast over b via mstride=0)
    const float* msrc = step == 0 ? mu : m;
    const int mstride = step == 0 ? 0 : C * K;
    kstep_kernel<false><<<dim3(N / NB, B), 256, 0, stream>>>(x, msrc, mstride,
                                                             mt, S, nullptr);
    kl2_kernel<<<dim3(K, B), 64, 0, stream>>>(mt, S, m);
  }
  kstep_kernel<true><<<dim3(N / NB, B), 256, 0, stream>>>(x, m, C * K, nullptr,
                                                          nullptr, out);
}